// Round 1
// baseline (1577.960 us; speedup 1.0000x reference)
//
#include <hip/hip_runtime.h>
#include <hip/hip_bf16.h>
#include <math.h>

// Problem constants
#define L_TOK 4096      // 64*64 output positions
#define D_DIM 576       // 9*64
#define QKV_LD 1728     // 3*576
#define NHEADS 8
#define DHEAD 72

// ---------------------------------------------------------------------------
// K1: unfold 3x3 stride 2 pad 1:  fea[1,64,128,128] -> x[4096][576]
// x[l, c*9 + ki*3 + kj] = fea[c, 2*ho+ki-1, 2*wo+kj-1] (0 if OOB), l = ho*64+wo
// ---------------------------------------------------------------------------
__global__ __launch_bounds__(256) void unfold_kernel(const float* __restrict__ fea,
                                                     float* __restrict__ x) {
  int idx = blockIdx.x * 256 + threadIdx.x;   // over 64*4096
  int c = idx >> 12;
  int l = idx & 4095;
  int ho = l >> 6, wo = l & 63;
  const float* f = fea + (size_t)c * (128 * 128);
  float* xr = x + (size_t)l * D_DIM + c * 9;
#pragma unroll
  for (int ki = 0; ki < 3; ki++) {
    int h = 2 * ho + ki - 1;
#pragma unroll
    for (int kj = 0; kj < 3; kj++) {
      int w = 2 * wo + kj - 1;
      float v = 0.f;
      if ((unsigned)h < 128u && (unsigned)w < 128u) v = f[h * 128 + w];
      xr[ki * 3 + kj] = v;
    }
  }
}

// ---------------------------------------------------------------------------
// K2/K4: tiled fp32 GEMM  C[M,N] = A[M,K] @ B[K,N] + bias (+ residual)
// B row-major [K][N]. 64x64 tile, 256 threads, 4x4 per thread, K-step 16.
// M, K multiples of 64/16; no bounds checks (exact shapes).
// ---------------------------------------------------------------------------
template <bool RES>
__global__ __launch_bounds__(256) void gemm_rowB(const float* __restrict__ A,
                                                 const float* __restrict__ B,
                                                 const float* __restrict__ bias,
                                                 const float* __restrict__ res,
                                                 float* __restrict__ C,
                                                 int N, int K) {
  __shared__ float As[16][68];   // [k][m], pad 68 -> 16B-aligned rows
  __shared__ float Bs[16][68];   // [k][n]
  const int t = threadIdx.x;
  const int tx = t & 15, ty = t >> 4;
  const int m0 = blockIdx.x * 64, n0 = blockIdx.y * 64;
  float acc[4][4] = {{0.f, 0.f, 0.f, 0.f}};

  for (int k0 = 0; k0 < K; k0 += 16) {
    const int kk = t & 15, mr = t >> 4;
#pragma unroll
    for (int r2 = 0; r2 < 4; r2++)
      As[kk][mr + 16 * r2] = A[(size_t)(m0 + mr + 16 * r2) * K + k0 + kk];
    const int nn = t & 63, kr = t >> 6;
#pragma unroll
    for (int r2 = 0; r2 < 4; r2++)
      Bs[kr * 4 + r2][nn] = B[(size_t)(k0 + kr * 4 + r2) * N + n0 + nn];
    __syncthreads();
#pragma unroll
    for (int kk2 = 0; kk2 < 16; kk2++) {
      float4 av = *(const float4*)&As[kk2][ty * 4];
      float4 bv = *(const float4*)&Bs[kk2][tx * 4];
      float a[4] = {av.x, av.y, av.z, av.w};
      float b[4] = {bv.x, bv.y, bv.z, bv.w};
#pragma unroll
      for (int i = 0; i < 4; i++)
#pragma unroll
        for (int j = 0; j < 4; j++) acc[i][j] += a[i] * b[j];
    }
    __syncthreads();
  }
#pragma unroll
  for (int i = 0; i < 4; i++) {
    int mrow = m0 + ty * 4 + i;
#pragma unroll
    for (int j = 0; j < 4; j++) {
      int ncol = n0 + tx * 4 + j;
      float v = acc[i][j] + bias[ncol];
      if (RES) v += res[(size_t)mrow * N + ncol];
      C[(size_t)mrow * N + ncol] = v;
    }
  }
}

// ---------------------------------------------------------------------------
// K3: flash attention, fp32. One WG = one head x 32-query block.
// qkv[4096][1728]: q at h*72, k at 576+h*72, v at 1152+h*72.
// 256 threads = 32 rows x 8 cols; each thread: 8 keys per tile, 9 out cols.
// ---------------------------------------------------------------------------
__global__ __launch_bounds__(256) void attn_kernel(const float* __restrict__ qkv,
                                                   float* __restrict__ o) {
  const int h = blockIdx.y;
  const int q0 = blockIdx.x * 32;
  const int t = threadIdx.x;
  const int r = t >> 3;   // 0..31: query row
  const int c8 = t & 7;   // 0..7

  __shared__ float Qs[32 * 72];
  __shared__ float Ks[64 * 76];  // pad 76: conflict-free float4 w/ k = kk*8+c8
  __shared__ float Vs[64 * 76];
  __shared__ float Ps[32 * 68];

  // load Q block
  for (int e = t; e < 32 * 72; e += 256) {
    int row = e / 72, d = e - row * 72;
    Qs[row * 72 + d] = qkv[(size_t)(q0 + row) * QKV_LD + h * DHEAD + d];
  }

  float m = -INFINITY, lsum = 0.f;
  float o_acc[9];
#pragma unroll
  for (int j = 0; j < 9; j++) o_acc[j] = 0.f;
  const float scale = 0.11785113019775792f;  // 72^-0.5

  for (int kt = 0; kt < 64; kt++) {
    __syncthreads();  // prev tile's P/V reads done before overwrite
    const int kbase = kt * 64;
    for (int e = t; e < 64 * 72; e += 256) {
      int row = e / 72, d = e - row * 72;
      size_t g = (size_t)(kbase + row) * QKV_LD + h * DHEAD + d;
      Ks[row * 76 + d] = qkv[g + 576];
      Vs[row * 76 + d] = qkv[g + 1152];
    }
    __syncthreads();

    // scores for 8 keys: k = kk*8 + c8
    float s[8];
#pragma unroll
    for (int kk = 0; kk < 8; kk++) s[kk] = 0.f;
    for (int d = 0; d < 72; d += 4) {
      float4 qv = *(const float4*)&Qs[r * 72 + d];
#pragma unroll
      for (int kk = 0; kk < 8; kk++) {
        float4 kv = *(const float4*)&Ks[(kk * 8 + c8) * 76 + d];
        s[kk] += qv.x * kv.x + qv.y * kv.y + qv.z * kv.z + qv.w * kv.w;
      }
    }
#pragma unroll
    for (int kk = 0; kk < 8; kk++) s[kk] *= scale;

    float tmax = s[0];
#pragma unroll
    for (int kk = 1; kk < 8; kk++) tmax = fmaxf(tmax, s[kk]);
    for (int off = 1; off < 8; off <<= 1) tmax = fmaxf(tmax, __shfl_xor(tmax, off, 8));
    float mnew = fmaxf(m, tmax);
    float alpha = __expf(m - mnew);  // m=-inf first tile -> 0

    float psum = 0.f;
#pragma unroll
    for (int kk = 0; kk < 8; kk++) {
      float p = __expf(s[kk] - mnew);
      psum += p;
      Ps[r * 68 + kk * 8 + c8] = p;
    }
    for (int off = 1; off < 8; off <<= 1) psum += __shfl_xor(psum, off, 8);
    lsum = lsum * alpha + psum;
    m = mnew;
    __syncthreads();  // P visible to whole row

    // PV: cols j*8 + c8
#pragma unroll
    for (int j = 0; j < 9; j++) o_acc[j] *= alpha;
    for (int k = 0; k < 64; k++) {
      float p = Ps[r * 68 + k];
#pragma unroll
      for (int j = 0; j < 9; j++) o_acc[j] += p * Vs[k * 76 + j * 8 + c8];
    }
  }

  float inv = 1.f / lsum;
#pragma unroll
  for (int j = 0; j < 9; j++)
    o[(size_t)(q0 + r) * D_DIM + h * DHEAD + j * 8 + c8] = o_acc[j] * inv;
}

// ---------------------------------------------------------------------------
// K5: final  out[oc][l] = silu( sum_d xr[l][d] * conv_w[oc][d] )
// conv_w is [128][576] row-major (N x K). 64x64 tile.
// ---------------------------------------------------------------------------
__global__ __launch_bounds__(256) void final_kernel(const float* __restrict__ A,
                                                    const float* __restrict__ Bt,
                                                    float* __restrict__ out) {
  __shared__ float As[16][68];
  __shared__ float Bs[16][68];
  const int t = threadIdx.x;
  const int tx = t & 15, ty = t >> 4;
  const int m0 = blockIdx.x * 64, n0 = blockIdx.y * 64;
  float acc[4][4] = {{0.f, 0.f, 0.f, 0.f}};

  for (int k0 = 0; k0 < 576; k0 += 16) {
    const int kk = t & 15, mr = t >> 4;
#pragma unroll
    for (int r2 = 0; r2 < 4; r2++) {
      As[kk][mr + 16 * r2] = A[(size_t)(m0 + mr + 16 * r2) * 576 + k0 + kk];
      Bs[kk][mr + 16 * r2] = Bt[(size_t)(n0 + mr + 16 * r2) * 576 + k0 + kk];
    }
    __syncthreads();
#pragma unroll
    for (int kk2 = 0; kk2 < 16; kk2++) {
      float4 av = *(const float4*)&As[kk2][ty * 4];
      float4 bv = *(const float4*)&Bs[kk2][tx * 4];
      float a[4] = {av.x, av.y, av.z, av.w};
      float b[4] = {bv.x, bv.y, bv.z, bv.w};
#pragma unroll
      for (int i = 0; i < 4; i++)
#pragma unroll
        for (int j = 0; j < 4; j++) acc[i][j] += a[i] * b[j];
    }
    __syncthreads();
  }
#pragma unroll
  for (int i = 0; i < 4; i++) {
    int l = m0 + ty * 4 + i;
#pragma unroll
    for (int j = 0; j < 4; j++) {
      int oc = n0 + tx * 4 + j;
      float v = acc[i][j];
      float sg = 1.f / (1.f + __expf(-v));
      out[(size_t)oc * L_TOK + l] = v * sg;
    }
  }
}

// ---------------------------------------------------------------------------
extern "C" void kernel_launch(void* const* d_in, const int* in_sizes, int n_in,
                              void* d_out, int out_size, void* d_ws, size_t ws_size,
                              hipStream_t stream) {
  const float* fea    = (const float*)d_in[0];
  const float* w_qkv  = (const float*)d_in[1];
  const float* b_qkv  = (const float*)d_in[2];
  const float* w_out  = (const float*)d_in[3];
  const float* b_out  = (const float*)d_in[4];
  const float* conv_w = (const float*)d_in[5];
  float* out = (float*)d_out;

  // workspace layout (floats): x | qkv | o | xr  = 56.6 MB total
  float* x   = (float*)d_ws;
  float* qkv = x + (size_t)L_TOK * D_DIM;
  float* o   = qkv + (size_t)L_TOK * QKV_LD;
  float* xr  = o + (size_t)L_TOK * D_DIM;

  unfold_kernel<<<1024, 256, 0, stream>>>(fea, x);
  gemm_rowB<false><<<dim3(64, 27), 256, 0, stream>>>(x, w_qkv, b_qkv, nullptr, qkv,
                                                     QKV_LD, D_DIM);
  attn_kernel<<<dim3(128, NHEADS), 256, 0, stream>>>(qkv, o);
  gemm_rowB<true><<<dim3(64, 9), 256, 0, stream>>>(o, w_out, b_out, x, xr,
                                                   D_DIM, D_DIM);
  final_kernel<<<dim3(64, 2), 256, 0, stream>>>(xr, conv_w, out);
}

// Round 2
// 498.335 us; speedup vs baseline: 3.1665x; 3.1665x over previous
//
#include <hip/hip_runtime.h>
#include <hip/hip_bf16.h>
#include <math.h>

// Problem constants
#define L_TOK 4096      // 64*64 output positions
#define D_DIM 576       // 9*64
#define QKV_LD 1728     // 3*576
#define NHEADS 8
#define DHEAD 72
#define DPAD 96         // head dim padded to 3*32 for K=32 MFMA steps

typedef __attribute__((ext_vector_type(8))) short short8;
typedef __attribute__((ext_vector_type(4))) float float4v;

union F4S8 {
  float4 f4;
  short8 s8;
  __hip_bfloat16 h[8];
};

// ---------------------------------------------------------------------------
// K1: unfold 3x3 stride 2 pad 1:  fea[1,64,128,128] -> x[4096][576]
// ---------------------------------------------------------------------------
__global__ __launch_bounds__(256) void unfold_kernel(const float* __restrict__ fea,
                                                     float* __restrict__ x) {
  int idx = blockIdx.x * 256 + threadIdx.x;   // over 64*4096
  int c = idx >> 12;
  int l = idx & 4095;
  int ho = l >> 6, wo = l & 63;
  const float* f = fea + (size_t)c * (128 * 128);
  float* xr = x + (size_t)l * D_DIM + c * 9;
#pragma unroll
  for (int ki = 0; ki < 3; ki++) {
    int h = 2 * ho + ki - 1;
#pragma unroll
    for (int kj = 0; kj < 3; kj++) {
      int w = 2 * wo + kj - 1;
      float v = 0.f;
      if ((unsigned)h < 128u && (unsigned)w < 128u) v = f[h * 128 + w];
      xr[ki * 3 + kj] = v;
    }
  }
}

// ---------------------------------------------------------------------------
// K2: QKV GEMM (fp32 accumulate) writing bf16 Q/K/V in [h][4096][96] layout.
// qkv col n = part*576 + h*72 + d.  Pad columns d=72..95 pre-zeroed by memset.
// ---------------------------------------------------------------------------
__global__ __launch_bounds__(256) void gemm_qkv(const float* __restrict__ A,
                                                const float* __restrict__ B,
                                                const float* __restrict__ bias,
                                                __hip_bfloat16* __restrict__ Qb,
                                                __hip_bfloat16* __restrict__ Kb,
                                                __hip_bfloat16* __restrict__ Vb) {
  __shared__ float As[16][68];
  __shared__ float Bs[16][68];
  const int t = threadIdx.x;
  const int tx = t & 15, ty = t >> 4;
  const int m0 = blockIdx.x * 64, n0 = blockIdx.y * 64;
  float acc[4][4] = {{0.f, 0.f, 0.f, 0.f}};

  for (int k0 = 0; k0 < D_DIM; k0 += 16) {
    const int kk = t & 15, mr = t >> 4;
#pragma unroll
    for (int r2 = 0; r2 < 4; r2++)
      As[kk][mr + 16 * r2] = A[(size_t)(m0 + mr + 16 * r2) * D_DIM + k0 + kk];
    const int nn = t & 63, kr = t >> 6;
#pragma unroll
    for (int r2 = 0; r2 < 4; r2++)
      Bs[kr * 4 + r2][nn] = B[(size_t)(k0 + kr * 4 + r2) * QKV_LD + n0 + nn];
    __syncthreads();
#pragma unroll
    for (int kk2 = 0; kk2 < 16; kk2++) {
      float4 av = *(const float4*)&As[kk2][ty * 4];
      float4 bv = *(const float4*)&Bs[kk2][tx * 4];
      float a[4] = {av.x, av.y, av.z, av.w};
      float b[4] = {bv.x, bv.y, bv.z, bv.w};
#pragma unroll
      for (int i = 0; i < 4; i++)
#pragma unroll
        for (int j = 0; j < 4; j++) acc[i][j] += a[i] * b[j];
    }
    __syncthreads();
  }
#pragma unroll
  for (int i = 0; i < 4; i++) {
    int m = m0 + ty * 4 + i;
#pragma unroll
    for (int j = 0; j < 4; j++) {
      int n = n0 + tx * 4 + j;
      float v = acc[i][j] + bias[n];
      int part = n / D_DIM;
      int rem = n - part * D_DIM;
      int h = rem / DHEAD;
      int d = rem - h * DHEAD;
      __hip_bfloat16* dst = (part == 0) ? Qb : (part == 1) ? Kb : Vb;
      dst[((size_t)h * L_TOK + m) * DPAD + d] = __float2bfloat16(v);
    }
  }
}

// ---------------------------------------------------------------------------
// K3: bf16 MFMA flash attention.
// 1 WG = (head, 64-query block); 4 waves x 16 queries; K/V tiles of 64 keys.
// mfma_f32_16x16x32_bf16 layouts:
//   A[m=lane&15][k=quad*8+j], B[k=quad*8+j][n=lane&15],
//   C/D: col=lane&15, row=quad*4+reg.
// ---------------------------------------------------------------------------
#define KS_STRIDE 104   // 208B rows: 16B aligned, 2-way bank aliasing (free)
#define VT_STRIDE 72    // 144B rows: 16B aligned, 2-way
#define PS_STRIDE 72

__global__ __launch_bounds__(256) void attn_mfma(const __hip_bfloat16* __restrict__ Qb,
                                                 const __hip_bfloat16* __restrict__ Kb,
                                                 const __hip_bfloat16* __restrict__ Vb,
                                                 float* __restrict__ o) {
  __shared__ __align__(16) __hip_bfloat16 Ks[64 * KS_STRIDE];   // 13312 B
  __shared__ __align__(16) __hip_bfloat16 Vt[80 * VT_STRIDE];   // 11520 B (Vt[d][key])
  __shared__ __align__(16) __hip_bfloat16 Ps[4 * 16 * PS_STRIDE]; // 9216 B

  const int bid = blockIdx.x;
  const int h = bid & 7;            // XCD-affine: head h -> XCD h (heuristic)
  const int qblk = bid >> 3;
  const int t = threadIdx.x;
  const int wave = t >> 6;
  const int lane = t & 63;
  const int quad = lane >> 4;
  const int l16 = lane & 15;

  const __hip_bfloat16* Qh = Qb + (size_t)h * L_TOK * DPAD;
  const __hip_bfloat16* Kh = Kb + (size_t)h * L_TOK * DPAD;
  const __hip_bfloat16* Vh = Vb + (size_t)h * L_TOK * DPAD;

  // Q fragments (A layout), resident all kernel: m=l16, k = s*32 + quad*8 + j
  const int qrow = qblk * 64 + wave * 16 + l16;
  short8 qf[3];
#pragma unroll
  for (int s = 0; s < 3; s++)
    qf[s] = *(const short8*)(Qh + (size_t)qrow * DPAD + s * 32 + quad * 8);

  float4v Of[5];
#pragma unroll
  for (int nt = 0; nt < 5; nt++) Of[nt] = (float4v){0.f, 0.f, 0.f, 0.f};
  float mrow[4] = {-INFINITY, -INFINITY, -INFINITY, -INFINITY};
  float lrow[4] = {0.f, 0.f, 0.f, 0.f};
  const float scale = 0.11785113019775792f;  // 72^-0.5

  __hip_bfloat16* myPs = Ps + wave * 16 * PS_STRIDE;

  for (int kt = 0; kt < 64; kt++) {
    const int kbase = kt * 64;
    __syncthreads();  // (a) prior tile's LDS reads complete

    // stage K tile: 64 rows x 96 elems = 768 16B-chunks (12 per row)
#pragma unroll
    for (int u = 0; u < 3; u++) {
      int e = t + u * 256;
      int row = e / 12, ch = e - row * 12;
      *(float4*)(&Ks[row * KS_STRIDE + ch * 8]) =
          *(const float4*)(Kh + (size_t)(kbase + row) * DPAD + ch * 8);
    }
    // stage V tile transposed: d<80 -> 640 chunks (10 per row), scatter to Vt[d][key]
    for (int e = t; e < 640; e += 256) {
      int row = e / 10, ch = e - row * 10;
      F4S8 u;
      u.f4 = *(const float4*)(Vh + (size_t)(kbase + row) * DPAD + ch * 8);
#pragma unroll
      for (int j = 0; j < 8; j++) Vt[(ch * 8 + j) * VT_STRIDE + row] = u.h[j];
    }
    __syncthreads();  // (b) staging visible

    // S = Q K^T : 4 key-subtiles x 3 K-steps
    float4v S[4];
#pragma unroll
    for (int ks = 0; ks < 4; ks++) {
      float4v acc = (float4v){0.f, 0.f, 0.f, 0.f};
#pragma unroll
      for (int s = 0; s < 3; s++) {
        short8 bf = *(const short8*)(&Ks[(ks * 16 + l16) * KS_STRIDE + s * 32 + quad * 8]);
        acc = __builtin_amdgcn_mfma_f32_16x16x32_bf16(qf[s], bf, acc, 0, 0, 0);
      }
#pragma unroll
      for (int r = 0; r < 4; r++) S[ks][r] = acc[r] * scale;
    }

    // online softmax per row (row = quad*4 + r, replicated over 16 lanes)
    float alpha[4];
#pragma unroll
    for (int r = 0; r < 4; r++) {
      float tm = fmaxf(fmaxf(S[0][r], S[1][r]), fmaxf(S[2][r], S[3][r]));
#pragma unroll
      for (int off = 1; off < 16; off <<= 1) tm = fmaxf(tm, __shfl_xor(tm, off));
      float mnew = fmaxf(mrow[r], tm);
      alpha[r] = __expf(mrow[r] - mnew);
      mrow[r] = mnew;
      float ps = 0.f;
#pragma unroll
      for (int ks = 0; ks < 4; ks++) {
        float p = __expf(S[ks][r] - mnew);
        ps += p;
        S[ks][r] = p;
      }
#pragma unroll
      for (int off = 1; off < 16; off <<= 1) ps += __shfl_xor(ps, off);
      lrow[r] = lrow[r] * alpha[r] + ps;
    }

    // P -> LDS (C layout -> A layout round trip), per-wave region
#pragma unroll
    for (int ks = 0; ks < 4; ks++)
#pragma unroll
      for (int r = 0; r < 4; r++)
        myPs[(quad * 4 + r) * PS_STRIDE + ks * 16 + l16] = __float2bfloat16(S[ks][r]);
    __syncthreads();  // (c) P visible / ordered

    // O = O*alpha + P V : 5 d-tiles x 2 K-steps
#pragma unroll
    for (int nt = 0; nt < 5; nt++)
#pragma unroll
      for (int r = 0; r < 4; r++) Of[nt][r] *= alpha[r];
#pragma unroll
    for (int kstep = 0; kstep < 2; kstep++) {
      short8 pa = *(const short8*)(&myPs[l16 * PS_STRIDE + kstep * 32 + quad * 8]);
#pragma unroll
      for (int nt = 0; nt < 5; nt++) {
        short8 vb = *(const short8*)(&Vt[(nt * 16 + l16) * VT_STRIDE + kstep * 32 + quad * 8]);
        Of[nt] = __builtin_amdgcn_mfma_f32_16x16x32_bf16(pa, vb, Of[nt], 0, 0, 0);
      }
    }
  }

  // epilogue: divide by l, store fp32 o[q][h*72+d]
  float inv[4];
#pragma unroll
  for (int r = 0; r < 4; r++) inv[r] = 1.f / lrow[r];
#pragma unroll
  for (int nt = 0; nt < 5; nt++) {
    int d = nt * 16 + l16;
    if (d < DHEAD) {
#pragma unroll
      for (int r = 0; r < 4; r++) {
        int q = qblk * 64 + wave * 16 + quad * 4 + r;
        o[(size_t)q * D_DIM + h * DHEAD + d] = Of[nt][r] * inv[r];
      }
    }
  }
}

// ---------------------------------------------------------------------------
// K4: out-proj GEMM + bias + residual (fp32)
// ---------------------------------------------------------------------------
__global__ __launch_bounds__(256) void gemm_oproj(const float* __restrict__ A,
                                                  const float* __restrict__ B,
                                                  const float* __restrict__ bias,
                                                  const float* __restrict__ res,
                                                  float* __restrict__ C) {
  __shared__ float As[16][68];
  __shared__ float Bs[16][68];
  const int t = threadIdx.x;
  const int tx = t & 15, ty = t >> 4;
  const int m0 = blockIdx.x * 64, n0 = blockIdx.y * 64;
  float acc[4][4] = {{0.f, 0.f, 0.f, 0.f}};

  for (int k0 = 0; k0 < D_DIM; k0 += 16) {
    const int kk = t & 15, mr = t >> 4;
#pragma unroll
    for (int r2 = 0; r2 < 4; r2++)
      As[kk][mr + 16 * r2] = A[(size_t)(m0 + mr + 16 * r2) * D_DIM + k0 + kk];
    const int nn = t & 63, kr = t >> 6;
#pragma unroll
    for (int r2 = 0; r2 < 4; r2++)
      Bs[kr * 4 + r2][nn] = B[(size_t)(k0 + kr * 4 + r2) * D_DIM + n0 + nn];
    __syncthreads();
#pragma unroll
    for (int kk2 = 0; kk2 < 16; kk2++) {
      float4 av = *(const float4*)&As[kk2][ty * 4];
      float4 bv = *(const float4*)&Bs[kk2][tx * 4];
      float a[4] = {av.x, av.y, av.z, av.w};
      float b[4] = {bv.x, bv.y, bv.z, bv.w};
#pragma unroll
      for (int i = 0; i < 4; i++)
#pragma unroll
        for (int j = 0; j < 4; j++) acc[i][j] += a[i] * b[j];
    }
    __syncthreads();
  }
#pragma unroll
  for (int i = 0; i < 4; i++) {
    int mrow = m0 + ty * 4 + i;
#pragma unroll
    for (int j = 0; j < 4; j++) {
      int ncol = n0 + tx * 4 + j;
      float v = acc[i][j] + bias[ncol] + res[(size_t)mrow * D_DIM + ncol];
      C[(size_t)mrow * D_DIM + ncol] = v;
    }
  }
}

// ---------------------------------------------------------------------------
// K5: final  out[oc][l] = silu( sum_d xr[l][d] * conv_w[oc][d] )
// ---------------------------------------------------------------------------
__global__ __launch_bounds__(256) void final_kernel(const float* __restrict__ A,
                                                    const float* __restrict__ Bt,
                                                    float* __restrict__ out) {
  __shared__ float As[16][68];
  __shared__ float Bs[16][68];
  const int t = threadIdx.x;
  const int tx = t & 15, ty = t >> 4;
  const int m0 = blockIdx.x * 64, n0 = blockIdx.y * 64;
  float acc[4][4] = {{0.f, 0.f, 0.f, 0.f}};

  for (int k0 = 0; k0 < 576; k0 += 16) {
    const int kk = t & 15, mr = t >> 4;
#pragma unroll
    for (int r2 = 0; r2 < 4; r2++) {
      As[kk][mr + 16 * r2] = A[(size_t)(m0 + mr + 16 * r2) * 576 + k0 + kk];
      Bs[kk][mr + 16 * r2] = Bt[(size_t)(n0 + mr + 16 * r2) * 576 + k0 + kk];
    }
    __syncthreads();
#pragma unroll
    for (int kk2 = 0; kk2 < 16; kk2++) {
      float4 av = *(const float4*)&As[kk2][ty * 4];
      float4 bv = *(const float4*)&Bs[kk2][tx * 4];
      float a[4] = {av.x, av.y, av.z, av.w};
      float b[4] = {bv.x, bv.y, bv.z, bv.w};
#pragma unroll
      for (int i = 0; i < 4; i++)
#pragma unroll
        for (int j = 0; j < 4; j++) acc[i][j] += a[i] * b[j];
    }
    __syncthreads();
  }
#pragma unroll
  for (int i = 0; i < 4; i++) {
    int l = m0 + ty * 4 + i;
#pragma unroll
    for (int j = 0; j < 4; j++) {
      int oc = n0 + tx * 4 + j;
      float v = acc[i][j];
      float sg = 1.f / (1.f + __expf(-v));
      out[(size_t)oc * L_TOK + l] = v * sg;
    }
  }
}

// ---------------------------------------------------------------------------
extern "C" void kernel_launch(void* const* d_in, const int* in_sizes, int n_in,
                              void* d_out, int out_size, void* d_ws, size_t ws_size,
                              hipStream_t stream) {
  const float* fea    = (const float*)d_in[0];
  const float* w_qkv  = (const float*)d_in[1];
  const float* b_qkv  = (const float*)d_in[2];
  const float* w_out  = (const float*)d_in[3];
  const float* b_out  = (const float*)d_in[4];
  const float* conv_w = (const float*)d_in[5];
  float* out = (float*)d_out;

  // workspace layout: x(fp32) | Qb|Kb|Vb (bf16, [h][4096][96]) | o(fp32) | xr(fp32)
  float* x = (float*)d_ws;                                   // 9.44 MB
  __hip_bfloat16* Qb = (__hip_bfloat16*)(x + (size_t)L_TOK * D_DIM);
  __hip_bfloat16* Kb = Qb + (size_t)NHEADS * L_TOK * DPAD;   // each 6.29 MB
  __hip_bfloat16* Vb = Kb + (size_t)NHEADS * L_TOK * DPAD;
  float* o  = (float*)(Vb + (size_t)NHEADS * L_TOK * DPAD);  // 9.44 MB
  float* xr = o + (size_t)L_TOK * D_DIM;                     // 9.44 MB

  const size_t qkv_bytes = (size_t)NHEADS * L_TOK * DPAD * sizeof(__hip_bfloat16);
  hipMemsetAsync(Qb, 0, qkv_bytes * 3, stream);  // zero pad cols d=72..95

  unfold_kernel<<<1024, 256, 0, stream>>>(fea, x);
  gemm_qkv<<<dim3(64, 27), 256, 0, stream>>>(x, w_qkv, b_qkv, Qb, Kb, Vb);
  attn_mfma<<<512, 256, 0, stream>>>(Qb, Kb, Vb, o);
  gemm_oproj<<<dim3(64, 9), 256, 0, stream>>>(o, w_out, b_out, x, xr);
  final_kernel<<<dim3(64, 2), 256, 0, stream>>>(xr, conv_w, out);
}

// Round 3
// 335.525 us; speedup vs baseline: 4.7030x; 1.4852x over previous
//
#include <hip/hip_runtime.h>
#include <hip/hip_bf16.h>
#include <math.h>

#define L_TOK 4096
#define D_DIM 576
#define NHEADS 8
#define DHEAD 72
#define DPAD 96
#define HSZ ((size_t)NHEADS * L_TOK * DPAD)   // elems per Q/K/V tensor

typedef __attribute__((ext_vector_type(8))) short short8;
typedef __attribute__((ext_vector_type(4))) float float4v;

union F4S8 {
  float4 f4;
  short8 s8;
  __hip_bfloat16 h[8];
};

// ---------------------------------------------------------------------------
// K1: unfold 3x3 stride 2 pad 1 -> xb bf16 [4096][576]
// ---------------------------------------------------------------------------
__global__ __launch_bounds__(256) void unfold_kernel(const float* __restrict__ fea,
                                                     __hip_bfloat16* __restrict__ x) {
  int idx = blockIdx.x * 256 + threadIdx.x;   // over 64*4096
  int c = idx >> 12;
  int l = idx & 4095;
  int ho = l >> 6, wo = l & 63;
  const float* f = fea + (size_t)c * (128 * 128);
  __hip_bfloat16* xr = x + (size_t)l * D_DIM + c * 9;
#pragma unroll
  for (int ki = 0; ki < 3; ki++) {
    int h = 2 * ho + ki - 1;
#pragma unroll
    for (int kj = 0; kj < 3; kj++) {
      int w = 2 * wo + kj - 1;
      float v = 0.f;
      if ((unsigned)h < 128u && (unsigned)w < 128u) v = f[h * 128 + w];
      xr[ki * 3 + kj] = __float2bfloat16(v);
    }
  }
}

// ---------------------------------------------------------------------------
// transpose+convert: src fp32 [R][C] -> dst bf16 [C][R]; R,C multiples of 64
// ---------------------------------------------------------------------------
__global__ __launch_bounds__(256) void transpose_cvt(const float* __restrict__ src,
                                                     __hip_bfloat16* __restrict__ dst,
                                                     int R, int C) {
  __shared__ __hip_bfloat16 Ts[64 * 68];
  const int bi = blockIdx.x;  // over C/64
  const int bj = blockIdx.y;  // over R/64
  const int t = threadIdx.x;
  const int col = t & 63, row4 = t >> 6;
#pragma unroll
  for (int u = 0; u < 16; u++) {
    int r = u * 4 + row4;
    Ts[r * 68 + col] = __float2bfloat16(src[(size_t)(bj * 64 + r) * C + bi * 64 + col]);
  }
  __syncthreads();
#pragma unroll
  for (int u = 0; u < 16; u++) {
    int c = u * 4 + row4;
    dst[(size_t)(bi * 64 + c) * R + bj * 64 + col] = Ts[col * 68 + c];
  }
}

// elementwise fp32 -> bf16
__global__ __launch_bounds__(256) void cvt_kernel(const float* __restrict__ src,
                                                  __hip_bfloat16* __restrict__ dst, int n) {
  int i = blockIdx.x * 256 + threadIdx.x;
  if (i < n) dst[i] = __float2bfloat16(src[i]);
}

// ---------------------------------------------------------------------------
// V transpose (once): Vb [h][4096][96] -> VbT [h][96][4096]
// ---------------------------------------------------------------------------
__global__ __launch_bounds__(256) void transpose_v(const __hip_bfloat16* __restrict__ Vb,
                                                   __hip_bfloat16* __restrict__ VbT) {
  __shared__ __hip_bfloat16 Ts[96 * 88];   // stride 88 elems (176B, 16B aligned)
  const int h = blockIdx.y;
  const int m0 = blockIdx.x * 64;
  const int t = threadIdx.x;
  const __hip_bfloat16* src = Vb + ((size_t)h * L_TOK + m0) * DPAD;
  const int m = t & 63;
#pragma unroll
  for (int u = 0; u < 3; u++) {
    int ch = u * 4 + (t >> 6);      // 0..11
    F4S8 x;
    x.f4 = *(const float4*)(src + (size_t)m * DPAD + ch * 8);
#pragma unroll
    for (int j = 0; j < 8; j++) Ts[(ch * 8 + j) * 88 + m] = x.h[j];
  }
  __syncthreads();
  __hip_bfloat16* dstb = VbT + (size_t)h * DPAD * L_TOK + m0;
  const int ch2 = t & 7;
#pragma unroll
  for (int u = 0; u < 3; u++) {
    int d = u * 32 + (t >> 3);      // 0..95
    *(float4*)(dstb + (size_t)d * L_TOK + ch2 * 8) = *(const float4*)(&Ts[d * 88 + ch2 * 8]);
  }
}

// ---------------------------------------------------------------------------
// bf16 MFMA GEMM: C[M][N] = A[M][576] @ Bt[N][576]^T (+epilogue)
// BM=128, BN=64, BK=64; 4 waves in 2x2 (wave m-tile 64, n-tile 32).
// EPI: 0 = QKV scatter(+bias), 1 = oproj(+bias+residual->bf16), 2 = SiLU+store^T
// ---------------------------------------------------------------------------
template <int EPI>
__global__ __launch_bounds__(256) void gemm_mfma(const __hip_bfloat16* __restrict__ A,
                                                 const __hip_bfloat16* __restrict__ Bt,
                                                 const float* __restrict__ bias,
                                                 const __hip_bfloat16* __restrict__ resid,
                                                 __hip_bfloat16* __restrict__ outB,
                                                 float* __restrict__ outF) {
  constexpr int K = D_DIM;
  __shared__ __align__(16) __hip_bfloat16 As[128 * 72];
  __shared__ __align__(16) __hip_bfloat16 Bs[64 * 72];
  const int t = threadIdx.x;
  const int wave = t >> 6, lane = t & 63, quad = lane >> 4, l16 = lane & 15;
  const int wm = (wave & 2) * 32;   // 0 or 64
  const int wn = (wave & 1) * 32;   // 0 or 32
  const int m0 = blockIdx.x * 128, n0 = blockIdx.y * 64;

  float4v acc[4][2];
#pragma unroll
  for (int i = 0; i < 4; i++)
#pragma unroll
    for (int j = 0; j < 2; j++) acc[i][j] = (float4v){0.f, 0.f, 0.f, 0.f};

  const int arow = t >> 3, ach = t & 7;
  for (int k0 = 0; k0 < K; k0 += 64) {
    __syncthreads();
#pragma unroll
    for (int u = 0; u < 4; u++) {
      int row = u * 32 + arow;
      *(float4*)(&As[row * 72 + ach * 8]) =
          *(const float4*)(A + (size_t)(m0 + row) * K + k0 + ach * 8);
    }
#pragma unroll
    for (int u = 0; u < 2; u++) {
      int row = u * 32 + arow;
      *(float4*)(&Bs[row * 72 + ach * 8]) =
          *(const float4*)(Bt + (size_t)(n0 + row) * K + k0 + ach * 8);
    }
    __syncthreads();
    short8 af[4][2], bfr[2][2];
#pragma unroll
    for (int i = 0; i < 4; i++)
#pragma unroll
      for (int s = 0; s < 2; s++)
        af[i][s] = *(const short8*)(&As[(wm + i * 16 + l16) * 72 + s * 32 + quad * 8]);
#pragma unroll
    for (int j = 0; j < 2; j++)
#pragma unroll
      for (int s = 0; s < 2; s++)
        bfr[j][s] = *(const short8*)(&Bs[(wn + j * 16 + l16) * 72 + s * 32 + quad * 8]);
#pragma unroll
    for (int i = 0; i < 4; i++)
#pragma unroll
      for (int j = 0; j < 2; j++) {
        acc[i][j] = __builtin_amdgcn_mfma_f32_16x16x32_bf16(af[i][0], bfr[j][0], acc[i][j], 0, 0, 0);
        acc[i][j] = __builtin_amdgcn_mfma_f32_16x16x32_bf16(af[i][1], bfr[j][1], acc[i][j], 0, 0, 0);
      }
  }

  // epilogue; C/D layout: col = l16 (n), row = quad*4 + r (m)
  if (EPI == 0) {
    const int part = n0 / D_DIM;          // block lies in exactly one of Q/K/V
    __hip_bfloat16* dst = outB + (size_t)part * HSZ;
#pragma unroll
    for (int j = 0; j < 2; j++) {
      int ng = n0 + wn + j * 16 + l16;
      float bv = bias[ng];
      int rem = ng - part * D_DIM;
      int h = rem / DHEAD;
      int d = rem - h * DHEAD;
#pragma unroll
      for (int i = 0; i < 4; i++) {
        int mb = m0 + wm + i * 16 + quad * 4;
#pragma unroll
        for (int r = 0; r < 4; r++)
          dst[((size_t)h * L_TOK + mb + r) * DPAD + d] = __float2bfloat16(acc[i][j][r] + bv);
      }
    }
  } else if (EPI == 1) {
#pragma unroll
    for (int j = 0; j < 2; j++) {
      int ng = n0 + wn + j * 16 + l16;
      float bv = bias[ng];
#pragma unroll
      for (int i = 0; i < 4; i++) {
        int mb = m0 + wm + i * 16 + quad * 4;
#pragma unroll
        for (int r = 0; r < 4; r++) {
          size_t idx = (size_t)(mb + r) * D_DIM + ng;
          float v = acc[i][j][r] + bv + __bfloat162float(resid[idx]);
          outB[idx] = __float2bfloat16(v);
        }
      }
    }
  } else {
#pragma unroll
    for (int j = 0; j < 2; j++) {
      int ng = n0 + wn + j * 16 + l16;   // output channel, <128
#pragma unroll
      for (int i = 0; i < 4; i++) {
        int mb = m0 + wm + i * 16 + quad * 4;
#pragma unroll
        for (int r = 0; r < 4; r++) {
          float v = acc[i][j][r];
          float sg = 1.f / (1.f + __expf(-v));
          outF[(size_t)ng * L_TOK + mb + r] = v * sg;
        }
      }
    }
  }
}

// ---------------------------------------------------------------------------
// bf16 MFMA flash attention. V pre-transposed: VbT [h][96][4096].
// ---------------------------------------------------------------------------
#define KS_STRIDE 104
#define VT_STRIDE 72
#define PS_STRIDE 72

__global__ __launch_bounds__(256) void attn_mfma(const __hip_bfloat16* __restrict__ Qb,
                                                 const __hip_bfloat16* __restrict__ Kb,
                                                 const __hip_bfloat16* __restrict__ VbT,
                                                 __hip_bfloat16* __restrict__ ob) {
  __shared__ __align__(16) __hip_bfloat16 Ks[64 * KS_STRIDE];
  __shared__ __align__(16) __hip_bfloat16 Vt[80 * VT_STRIDE];
  __shared__ __align__(16) __hip_bfloat16 Ps[4 * 16 * PS_STRIDE];

  const int bid = blockIdx.x;
  const int h = bid & 7;
  const int qblk = bid >> 3;
  const int t = threadIdx.x;
  const int wave = t >> 6;
  const int lane = t & 63;
  const int quad = lane >> 4;
  const int l16 = lane & 15;

  const __hip_bfloat16* Qh = Qb + (size_t)h * L_TOK * DPAD;
  const __hip_bfloat16* Kh = Kb + (size_t)h * L_TOK * DPAD;
  const __hip_bfloat16* VhT = VbT + (size_t)h * DPAD * L_TOK;

  const int qrow = qblk * 64 + wave * 16 + l16;
  short8 qf[3];
#pragma unroll
  for (int s = 0; s < 3; s++)
    qf[s] = *(const short8*)(Qh + (size_t)qrow * DPAD + s * 32 + quad * 8);

  float4v Of[5];
#pragma unroll
  for (int nt = 0; nt < 5; nt++) Of[nt] = (float4v){0.f, 0.f, 0.f, 0.f};
  float mrow[4] = {-INFINITY, -INFINITY, -INFINITY, -INFINITY};
  float lrow[4] = {0.f, 0.f, 0.f, 0.f};
  const float scale = 0.11785113019775792f;  // 72^-0.5

  __hip_bfloat16* myPs = Ps + wave * 16 * PS_STRIDE;

  for (int kt = 0; kt < 64; kt++) {
    const int kbase = kt * 64;
    __syncthreads();

    // stage K tile [64 keys][96 d]
#pragma unroll
    for (int u = 0; u < 3; u++) {
      int e = t + u * 256;
      int row = e / 12, ch = e - row * 12;
      *(float4*)(&Ks[row * KS_STRIDE + ch * 8]) =
          *(const float4*)(Kh + (size_t)(kbase + row) * DPAD + ch * 8);
    }
    // stage V^T tile [80 d][64 keys] straight from VbT (vectorized, no scatter)
    for (int e = t; e < 640; e += 256) {
      int d = e >> 3, ch = e & 7;
      *(float4*)(&Vt[d * VT_STRIDE + ch * 8]) =
          *(const float4*)(VhT + (size_t)d * L_TOK + kbase + ch * 8);
    }
    __syncthreads();

    // S = Q K^T
    float4v S[4];
#pragma unroll
    for (int ks = 0; ks < 4; ks++) {
      float4v acc = (float4v){0.f, 0.f, 0.f, 0.f};
#pragma unroll
      for (int s = 0; s < 3; s++) {
        short8 bf = *(const short8*)(&Ks[(ks * 16 + l16) * KS_STRIDE + s * 32 + quad * 8]);
        acc = __builtin_amdgcn_mfma_f32_16x16x32_bf16(qf[s], bf, acc, 0, 0, 0);
      }
#pragma unroll
      for (int r = 0; r < 4; r++) S[ks][r] = acc[r] * scale;
    }

    // online softmax (row = quad*4 + r)
    float alpha[4];
#pragma unroll
    for (int r = 0; r < 4; r++) {
      float tm = fmaxf(fmaxf(S[0][r], S[1][r]), fmaxf(S[2][r], S[3][r]));
#pragma unroll
      for (int off = 1; off < 16; off <<= 1) tm = fmaxf(tm, __shfl_xor(tm, off));
      float mnew = fmaxf(mrow[r], tm);
      alpha[r] = __expf(mrow[r] - mnew);
      mrow[r] = mnew;
      float ps = 0.f;
#pragma unroll
      for (int ks = 0; ks < 4; ks++) {
        float p = __expf(S[ks][r] - mnew);
        ps += p;
        S[ks][r] = p;
      }
#pragma unroll
      for (int off = 1; off < 16; off <<= 1) ps += __shfl_xor(ps, off);
      lrow[r] = lrow[r] * alpha[r] + ps;
    }

    // P: C layout -> A layout via per-wave LDS region
#pragma unroll
    for (int ks = 0; ks < 4; ks++)
#pragma unroll
      for (int r = 0; r < 4; r++)
        myPs[(quad * 4 + r) * PS_STRIDE + ks * 16 + l16] = __float2bfloat16(S[ks][r]);
    __syncthreads();

    // O = O*alpha + P V
#pragma unroll
    for (int nt = 0; nt < 5; nt++)
#pragma unroll
      for (int r = 0; r < 4; r++) Of[nt][r] *= alpha[r];
#pragma unroll
    for (int kstep = 0; kstep < 2; kstep++) {
      short8 pa = *(const short8*)(&myPs[l16 * PS_STRIDE + kstep * 32 + quad * 8]);
#pragma unroll
      for (int nt = 0; nt < 5; nt++) {
        short8 vb = *(const short8*)(&Vt[(nt * 16 + l16) * VT_STRIDE + kstep * 32 + quad * 8]);
        Of[nt] = __builtin_amdgcn_mfma_f32_16x16x32_bf16(pa, vb, Of[nt], 0, 0, 0);
      }
    }
  }

  float inv[4];
#pragma unroll
  for (int r = 0; r < 4; r++) inv[r] = 1.f / lrow[r];
#pragma unroll
  for (int nt = 0; nt < 5; nt++) {
    int d = nt * 16 + l16;
    if (d < DHEAD) {
#pragma unroll
      for (int r = 0; r < 4; r++) {
        int q = qblk * 64 + wave * 16 + quad * 4 + r;
        ob[(size_t)q * D_DIM + h * DHEAD + d] = __float2bfloat16(Of[nt][r] * inv[r]);
      }
    }
  }
}

// ---------------------------------------------------------------------------
extern "C" void kernel_launch(void* const* d_in, const int* in_sizes, int n_in,
                              void* d_out, int out_size, void* d_ws, size_t ws_size,
                              hipStream_t stream) {
  const float* fea    = (const float*)d_in[0];
  const float* w_qkv  = (const float*)d_in[1];
  const float* b_qkv  = (const float*)d_in[2];
  const float* w_out  = (const float*)d_in[3];
  const float* b_out  = (const float*)d_in[4];
  const float* conv_w = (const float*)d_in[5];
  float* out = (float*)d_out;

  __hip_bfloat16* xb    = (__hip_bfloat16*)d_ws;             // 4096*576
  __hip_bfloat16* WqkvT = xb + (size_t)L_TOK * D_DIM;        // 1728*576
  __hip_bfloat16* WoT   = WqkvT + (size_t)1728 * D_DIM;      // 576*576
  __hip_bfloat16* CwB   = WoT + (size_t)D_DIM * D_DIM;       // 128*576
  __hip_bfloat16* QKVb  = CwB + (size_t)128 * D_DIM;         // 3 * HSZ
  __hip_bfloat16* VbT   = QKVb + 3 * HSZ;                    // HSZ
  __hip_bfloat16* ob    = VbT + HSZ;                         // 4096*576
  __hip_bfloat16* xr    = ob + (size_t)L_TOK * D_DIM;        // 4096*576

  hipMemsetAsync(QKVb, 0, 3 * HSZ * sizeof(__hip_bfloat16), stream);  // zero d-pad

  unfold_kernel<<<1024, 256, 0, stream>>>(fea, xb);
  transpose_cvt<<<dim3(27, 9), 256, 0, stream>>>(w_qkv, WqkvT, D_DIM, 1728);
  transpose_cvt<<<dim3(9, 9), 256, 0, stream>>>(w_out, WoT, D_DIM, D_DIM);
  cvt_kernel<<<288, 256, 0, stream>>>(conv_w, CwB, 128 * D_DIM);

  gemm_mfma<0><<<dim3(32, 27), 256, 0, stream>>>(xb, WqkvT, b_qkv, nullptr, QKVb, nullptr);
  transpose_v<<<dim3(64, 8), 256, 0, stream>>>(QKVb + 2 * HSZ, VbT);
  attn_mfma<<<512, 256, 0, stream>>>(QKVb, QKVb + HSZ, VbT, ob);
  gemm_mfma<1><<<dim3(32, 9), 256, 0, stream>>>(ob, WoT, b_out, xb, xr, nullptr);
  gemm_mfma<2><<<dim3(32, 2), 256, 0, stream>>>(xr, CwB, nullptr, nullptr, nullptr, out);
}

// Round 4
// 294.432 us; speedup vs baseline: 5.3593x; 1.1396x over previous
//
#include <hip/hip_runtime.h>
#include <hip/hip_bf16.h>
#include <math.h>

#define L_TOK 4096
#define D_DIM 576
#define NHEADS 8
#define DHEAD 72
#define DPAD 96
#define HSZ ((size_t)NHEADS * L_TOK * DPAD)   // elems per Q/K/V tensor

typedef __attribute__((ext_vector_type(8))) short short8;
typedef __attribute__((ext_vector_type(4))) float float4v;

// ---------------------------------------------------------------------------
// K1: unfold 3x3 stride 2 pad 1 -> xb bf16 [4096][576]
// ---------------------------------------------------------------------------
__global__ __launch_bounds__(256) void unfold_kernel(const float* __restrict__ fea,
                                                     __hip_bfloat16* __restrict__ x) {
  int idx = blockIdx.x * 256 + threadIdx.x;   // over 64*4096
  int c = idx >> 12;
  int l = idx & 4095;
  int ho = l >> 6, wo = l & 63;
  const float* f = fea + (size_t)c * (128 * 128);
  __hip_bfloat16* xr = x + (size_t)l * D_DIM + c * 9;
#pragma unroll
  for (int ki = 0; ki < 3; ki++) {
    int h = 2 * ho + ki - 1;
#pragma unroll
    for (int kj = 0; kj < 3; kj++) {
      int w = 2 * wo + kj - 1;
      float v = 0.f;
      if ((unsigned)h < 128u && (unsigned)w < 128u) v = f[h * 128 + w];
      xr[ki * 3 + kj] = __float2bfloat16(v);
    }
  }
}

// ---------------------------------------------------------------------------
// transpose+convert: src fp32 [R][C] -> dst bf16 [C][R]; R,C multiples of 64
// ---------------------------------------------------------------------------
__global__ __launch_bounds__(256) void transpose_cvt(const float* __restrict__ src,
                                                     __hip_bfloat16* __restrict__ dst,
                                                     int R, int C) {
  __shared__ __hip_bfloat16 Ts[64 * 68];
  const int bi = blockIdx.x;  // over C/64
  const int bj = blockIdx.y;  // over R/64
  const int t = threadIdx.x;
  const int col = t & 63, row4 = t >> 6;
#pragma unroll
  for (int u = 0; u < 16; u++) {
    int r = u * 4 + row4;
    Ts[r * 68 + col] = __float2bfloat16(src[(size_t)(bj * 64 + r) * C + bi * 64 + col]);
  }
  __syncthreads();
#pragma unroll
  for (int u = 0; u < 16; u++) {
    int c = u * 4 + row4;
    dst[(size_t)(bi * 64 + c) * R + bj * 64 + col] = Ts[col * 68 + c];
  }
}

// elementwise fp32 -> bf16
__global__ __launch_bounds__(256) void cvt_kernel(const float* __restrict__ src,
                                                  __hip_bfloat16* __restrict__ dst, int n) {
  int i = blockIdx.x * 256 + threadIdx.x;
  if (i < n) dst[i] = __float2bfloat16(src[i]);
}

// ---------------------------------------------------------------------------
// bf16 MFMA GEMM: C[M][N] = A[M][576] @ Bt[N][576]^T (+epilogue)
// BM=128, BN=64, BK=64; 4 waves in 2x2 (wave m-tile 64, n-tile 32).
// EPI: 0 = QKV scatter(+bias): Q,K -> [h][L][96]; V -> VbT [h][96][L]
//      1 = oproj(+bias+residual->bf16), 2 = SiLU+store^T (fp32 out)
// ---------------------------------------------------------------------------
template <int EPI>
__global__ __launch_bounds__(256) void gemm_mfma(const __hip_bfloat16* __restrict__ A,
                                                 const __hip_bfloat16* __restrict__ Bt,
                                                 const float* __restrict__ bias,
                                                 const __hip_bfloat16* __restrict__ resid,
                                                 __hip_bfloat16* __restrict__ outB,
                                                 __hip_bfloat16* __restrict__ outB2,
                                                 float* __restrict__ outF) {
  constexpr int K = D_DIM;
  __shared__ __align__(16) __hip_bfloat16 As[128 * 72];
  __shared__ __align__(16) __hip_bfloat16 Bs[64 * 72];
  const int t = threadIdx.x;
  const int wave = t >> 6, lane = t & 63, quad = lane >> 4, l16 = lane & 15;
  const int wm = (wave & 2) * 32;   // 0 or 64
  const int wn = (wave & 1) * 32;   // 0 or 32
  const int m0 = blockIdx.x * 128, n0 = blockIdx.y * 64;

  float4v acc[4][2];
#pragma unroll
  for (int i = 0; i < 4; i++)
#pragma unroll
    for (int j = 0; j < 2; j++) acc[i][j] = (float4v){0.f, 0.f, 0.f, 0.f};

  const int arow = t >> 3, ach = t & 7;
  for (int k0 = 0; k0 < K; k0 += 64) {
    __syncthreads();
#pragma unroll
    for (int u = 0; u < 4; u++) {
      int row = u * 32 + arow;
      *(float4*)(&As[row * 72 + ach * 8]) =
          *(const float4*)(A + (size_t)(m0 + row) * K + k0 + ach * 8);
    }
#pragma unroll
    for (int u = 0; u < 2; u++) {
      int row = u * 32 + arow;
      *(float4*)(&Bs[row * 72 + ach * 8]) =
          *(const float4*)(Bt + (size_t)(n0 + row) * K + k0 + ach * 8);
    }
    __syncthreads();
    short8 af[4][2], bfr[2][2];
#pragma unroll
    for (int i = 0; i < 4; i++)
#pragma unroll
      for (int s = 0; s < 2; s++)
        af[i][s] = *(const short8*)(&As[(wm + i * 16 + l16) * 72 + s * 32 + quad * 8]);
#pragma unroll
    for (int j = 0; j < 2; j++)
#pragma unroll
      for (int s = 0; s < 2; s++)
        bfr[j][s] = *(const short8*)(&Bs[(wn + j * 16 + l16) * 72 + s * 32 + quad * 8]);
#pragma unroll
    for (int i = 0; i < 4; i++)
#pragma unroll
      for (int j = 0; j < 2; j++) {
        acc[i][j] = __builtin_amdgcn_mfma_f32_16x16x32_bf16(af[i][0], bfr[j][0], acc[i][j], 0, 0, 0);
        acc[i][j] = __builtin_amdgcn_mfma_f32_16x16x32_bf16(af[i][1], bfr[j][1], acc[i][j], 0, 0, 0);
      }
  }

  // epilogue; C/D layout: col = l16 (n), row = quad*4 + r (m)
  if (EPI == 0) {
    const int part = n0 / D_DIM;          // block lies in exactly one of Q/K/V
#pragma unroll
    for (int j = 0; j < 2; j++) {
      int ng = n0 + wn + j * 16 + l16;
      float bv = bias[ng];
      int rem = ng - part * D_DIM;
      int h = rem / DHEAD;
      int d = rem - h * DHEAD;
#pragma unroll
      for (int i = 0; i < 4; i++) {
        int mb = m0 + wm + i * 16 + quad * 4;
#pragma unroll
        for (int r = 0; r < 4; r++) {
          float v = acc[i][j][r] + bv;
          if (part < 2) {
            __hip_bfloat16* dst = outB + (size_t)part * HSZ;
            dst[((size_t)h * L_TOK + mb + r) * DPAD + d] = __float2bfloat16(v);
          } else {
            outB2[((size_t)h * DPAD + d) * L_TOK + mb + r] = __float2bfloat16(v);
          }
        }
      }
    }
  } else if (EPI == 1) {
#pragma unroll
    for (int j = 0; j < 2; j++) {
      int ng = n0 + wn + j * 16 + l16;
      float bv = bias[ng];
#pragma unroll
      for (int i = 0; i < 4; i++) {
        int mb = m0 + wm + i * 16 + quad * 4;
#pragma unroll
        for (int r = 0; r < 4; r++) {
          size_t idx = (size_t)(mb + r) * D_DIM + ng;
          float v = acc[i][j][r] + bv + __bfloat162float(resid[idx]);
          outB[idx] = __float2bfloat16(v);
        }
      }
    }
  } else {
#pragma unroll
    for (int j = 0; j < 2; j++) {
      int ng = n0 + wn + j * 16 + l16;   // output channel, <128
#pragma unroll
      for (int i = 0; i < 4; i++) {
        int mb = m0 + wm + i * 16 + quad * 4;
#pragma unroll
        for (int r = 0; r < 4; r++) {
          float v = acc[i][j][r];
          float sg = 1.f / (1.f + __expf(-v));
          outF[(size_t)ng * L_TOK + mb + r] = v * sg;
        }
      }
    }
  }
}

// ---------------------------------------------------------------------------
// bf16 MFMA flash attention, K-split by 2.
// WG = 4 waves x 32 queries = 128 q; grid 512 = 8 heads x 2 ksplit x 32 qblk.
// Emits unnormalized partials Opart[ks][h][q][80] (bf16) + Ml[ks][h][q]{m,l}.
// Pads d=72..95 are zeroed in registers/staging (no global pad init needed).
// ---------------------------------------------------------------------------
#define KS_STRIDE 104
#define VT_STRIDE 72
#define PS_STRIDE 72

__global__ __launch_bounds__(256) void attn_mfma(const __hip_bfloat16* __restrict__ Qb,
                                                 const __hip_bfloat16* __restrict__ Kb,
                                                 const __hip_bfloat16* __restrict__ VbT,
                                                 __hip_bfloat16* __restrict__ Opart,
                                                 float* __restrict__ Ml) {
  __shared__ __align__(16) __hip_bfloat16 Ks[64 * KS_STRIDE];      // 13312 B
  __shared__ __align__(16) __hip_bfloat16 Vt[80 * VT_STRIDE];      // 11520 B
  __shared__ __align__(16) __hip_bfloat16 Ps[4 * 2 * 16 * PS_STRIDE]; // 18432 B

  const int bid = blockIdx.x;
  const int h = bid & 7;                  // head -> XCD affinity
  const int ksp = (bid >> 3) & 1;
  const int qblk = bid >> 4;              // 0..31
  const int t = threadIdx.x;
  const int wave = t >> 6;
  const int lane = t & 63;
  const int quad = lane >> 4;
  const int l16 = lane & 15;

  const __hip_bfloat16* Qh = Qb + (size_t)h * L_TOK * DPAD;
  const __hip_bfloat16* Kh = Kb + (size_t)h * L_TOK * DPAD;
  const __hip_bfloat16* VhT = VbT + (size_t)h * DPAD * L_TOK;

  const int qbase = qblk * 128 + wave * 32;
  short8 qf[2][3];
#pragma unroll
  for (int mi = 0; mi < 2; mi++) {
#pragma unroll
    for (int s = 0; s < 3; s++) {
      if (s == 2 && quad >= 1) {
        qf[mi][s] = (short8){0, 0, 0, 0, 0, 0, 0, 0};  // d>=72 pad
      } else {
        qf[mi][s] = *(const short8*)(Qh + (size_t)(qbase + mi * 16 + l16) * DPAD + s * 32 + quad * 8);
      }
    }
  }

  float4v Of[2][5];
#pragma unroll
  for (int mi = 0; mi < 2; mi++)
#pragma unroll
    for (int nt = 0; nt < 5; nt++) Of[mi][nt] = (float4v){0.f, 0.f, 0.f, 0.f};
  float mrow[2][4], lrow[2][4];
#pragma unroll
  for (int mi = 0; mi < 2; mi++)
#pragma unroll
    for (int r = 0; r < 4; r++) { mrow[mi][r] = -INFINITY; lrow[mi][r] = 0.f; }
  const float scale = 0.11785113019775792f;  // 72^-0.5

  __hip_bfloat16* myPs = Ps + wave * 2 * 16 * PS_STRIDE;
  const int kstart = ksp * 2048;
  const float4 zero4 = {0.f, 0.f, 0.f, 0.f};

  for (int kt = 0; kt < 32; kt++) {
    const int kbase = kstart + kt * 64;
    __syncthreads();  // prior tile's K/V reads complete

    // stage K tile [64 keys][96 d]; d>=72 forced to zero
#pragma unroll
    for (int u = 0; u < 3; u++) {
      int e = t + u * 256;
      int row = e / 12, ch = e - row * 12;
      if (ch >= 9) {
        *(float4*)(&Ks[row * KS_STRIDE + ch * 8]) = zero4;
      } else {
        *(float4*)(&Ks[row * KS_STRIDE + ch * 8]) =
            *(const float4*)(Kh + (size_t)(kbase + row) * DPAD + ch * 8);
      }
    }
    // stage V^T tile [80 d][64 keys]; rows d>=72 zero
    for (int e = t; e < 640; e += 256) {
      int d = e >> 3, ch = e & 7;
      if (d >= 72) {
        *(float4*)(&Vt[d * VT_STRIDE + ch * 8]) = zero4;
      } else {
        *(float4*)(&Vt[d * VT_STRIDE + ch * 8]) =
            *(const float4*)(VhT + (size_t)d * L_TOK + kbase + ch * 8);
      }
    }
    __syncthreads();

    // S = Q K^T (K frags shared across both m-frags)
    float4v S[2][4];
#pragma unroll
    for (int ks = 0; ks < 4; ks++) {
      float4v a0 = (float4v){0.f, 0.f, 0.f, 0.f};
      float4v a1 = (float4v){0.f, 0.f, 0.f, 0.f};
#pragma unroll
      for (int s = 0; s < 3; s++) {
        short8 bf = *(const short8*)(&Ks[(ks * 16 + l16) * KS_STRIDE + s * 32 + quad * 8]);
        a0 = __builtin_amdgcn_mfma_f32_16x16x32_bf16(qf[0][s], bf, a0, 0, 0, 0);
        a1 = __builtin_amdgcn_mfma_f32_16x16x32_bf16(qf[1][s], bf, a1, 0, 0, 0);
      }
#pragma unroll
      for (int r = 0; r < 4; r++) { S[0][ks][r] = a0[r] * scale; S[1][ks][r] = a1[r] * scale; }
    }

    // online softmax per m-frag, per row (row = quad*4 + r; cols = keys)
    float alpha[2][4];
#pragma unroll
    for (int mi = 0; mi < 2; mi++) {
#pragma unroll
      for (int r = 0; r < 4; r++) {
        float tm = fmaxf(fmaxf(S[mi][0][r], S[mi][1][r]), fmaxf(S[mi][2][r], S[mi][3][r]));
#pragma unroll
        for (int off = 1; off < 16; off <<= 1) tm = fmaxf(tm, __shfl_xor(tm, off));
        float mnew = fmaxf(mrow[mi][r], tm);
        alpha[mi][r] = __expf(mrow[mi][r] - mnew);
        mrow[mi][r] = mnew;
        float ps = 0.f;
#pragma unroll
        for (int ks = 0; ks < 4; ks++) {
          float p = __expf(S[mi][ks][r] - mnew);
          ps += p;
          S[mi][ks][r] = p;
        }
#pragma unroll
        for (int off = 1; off < 16; off <<= 1) ps += __shfl_xor(ps, off);
        lrow[mi][r] = lrow[mi][r] * alpha[mi][r] + ps;
      }
    }

    // P: C layout -> A layout via per-wave LDS region (same-wave ordering; no barrier)
#pragma unroll
    for (int mi = 0; mi < 2; mi++)
#pragma unroll
      for (int ks = 0; ks < 4; ks++)
#pragma unroll
        for (int r = 0; r < 4; r++)
          myPs[(mi * 16 + quad * 4 + r) * PS_STRIDE + ks * 16 + l16] = __float2bfloat16(S[mi][ks][r]);

    // O = O*alpha + P V (V frags shared across m-frags)
#pragma unroll
    for (int mi = 0; mi < 2; mi++)
#pragma unroll
      for (int nt = 0; nt < 5; nt++)
#pragma unroll
        for (int r = 0; r < 4; r++) Of[mi][nt][r] *= alpha[mi][r];
#pragma unroll
    for (int kstep = 0; kstep < 2; kstep++) {
      short8 pa0 = *(const short8*)(&myPs[(0 + l16) * PS_STRIDE + kstep * 32 + quad * 8]);
      short8 pa1 = *(const short8*)(&myPs[(16 + l16) * PS_STRIDE + kstep * 32 + quad * 8]);
#pragma unroll
      for (int nt = 0; nt < 5; nt++) {
        short8 vb = *(const short8*)(&Vt[(nt * 16 + l16) * VT_STRIDE + kstep * 32 + quad * 8]);
        Of[0][nt] = __builtin_amdgcn_mfma_f32_16x16x32_bf16(pa0, vb, Of[0][nt], 0, 0, 0);
        Of[1][nt] = __builtin_amdgcn_mfma_f32_16x16x32_bf16(pa1, vb, Of[1][nt], 0, 0, 0);
      }
    }
  }

  // store unnormalized partials + m,l
  const size_t pb = ((size_t)ksp * NHEADS + h) * L_TOK;
#pragma unroll
  for (int mi = 0; mi < 2; mi++) {
#pragma unroll
    for (int nt = 0; nt < 5; nt++) {
      int d = nt * 16 + l16;
#pragma unroll
      for (int r = 0; r < 4; r++) {
        int q = qbase + mi * 16 + quad * 4 + r;
        Opart[(pb + q) * 80 + d] = __float2bfloat16(Of[mi][nt][r]);
      }
    }
  }
  if (l16 == 0) {
#pragma unroll
    for (int mi = 0; mi < 2; mi++)
#pragma unroll
      for (int r = 0; r < 4; r++) {
        int q = qbase + mi * 16 + quad * 4 + r;
        Ml[(pb + q) * 2] = mrow[mi][r];
        Ml[(pb + q) * 2 + 1] = lrow[mi][r];
      }
  }
}

// ---------------------------------------------------------------------------
// flash-merge of the 2 K-split partials -> ob[q][h*72+d] bf16
// ---------------------------------------------------------------------------
__global__ __launch_bounds__(256) void attn_merge(const __hip_bfloat16* __restrict__ Opart,
                                                  const float* __restrict__ Ml,
                                                  __hip_bfloat16* __restrict__ ob) {
  int idx = blockIdx.x * 256 + threadIdx.x;     // 8h * 4096q * 9ch
  int h = idx / (L_TOK * 9);
  int rem = idx - h * (L_TOK * 9);
  int q = rem / 9;
  int ch = rem - q * 9;
  size_t b0 = (size_t)h * L_TOK + q;
  size_t b1 = ((size_t)NHEADS + h) * L_TOK + q;
  float m0 = Ml[b0 * 2], l0 = Ml[b0 * 2 + 1];
  float m1 = Ml[b1 * 2], l1 = Ml[b1 * 2 + 1];
  float mx = fmaxf(m0, m1);
  float w0 = __expf(m0 - mx), w1 = __expf(m1 - mx);
  float inv = 1.f / (w0 * l0 + w1 * l1);
  short8 o0 = *(const short8*)(Opart + b0 * 80 + ch * 8);
  short8 o1 = *(const short8*)(Opart + b1 * 80 + ch * 8);
  __hip_bfloat16* dst = ob + (size_t)q * D_DIM + h * DHEAD + ch * 8;
#pragma unroll
  for (int j = 0; j < 8; j++) {
    union { short s; __hip_bfloat16 b; } u0, u1;
    u0.s = o0[j]; u1.s = o1[j];
    float v = (w0 * __bfloat162float(u0.b) + w1 * __bfloat162float(u1.b)) * inv;
    dst[j] = __float2bfloat16(v);
  }
}

// ---------------------------------------------------------------------------
extern "C" void kernel_launch(void* const* d_in, const int* in_sizes, int n_in,
                              void* d_out, int out_size, void* d_ws, size_t ws_size,
                              hipStream_t stream) {
  const float* fea    = (const float*)d_in[0];
  const float* w_qkv  = (const float*)d_in[1];
  const float* b_qkv  = (const float*)d_in[2];
  const float* w_out  = (const float*)d_in[3];
  const float* b_out  = (const float*)d_in[4];
  const float* conv_w = (const float*)d_in[5];
  float* out = (float*)d_out;

  __hip_bfloat16* xb    = (__hip_bfloat16*)d_ws;             // 4096*576
  __hip_bfloat16* WqkvT = xb + (size_t)L_TOK * D_DIM;        // 1728*576
  __hip_bfloat16* WoT   = WqkvT + (size_t)1728 * D_DIM;      // 576*576
  __hip_bfloat16* CwB   = WoT + (size_t)D_DIM * D_DIM;       // 128*576
  __hip_bfloat16* QKb   = CwB + (size_t)128 * D_DIM;         // 2 * HSZ (Q,K)
  __hip_bfloat16* VbT   = QKb + 2 * HSZ;                     // HSZ
  __hip_bfloat16* ob    = VbT + HSZ;                         // 4096*576
  __hip_bfloat16* xr    = ob + (size_t)L_TOK * D_DIM;        // 4096*576
  __hip_bfloat16* Opart = xr + (size_t)L_TOK * D_DIM;        // 2*8*4096*80
  float* Ml = (float*)(Opart + (size_t)2 * NHEADS * L_TOK * 80);  // 2*8*4096*2

  unfold_kernel<<<1024, 256, 0, stream>>>(fea, xb);
  transpose_cvt<<<dim3(27, 9), 256, 0, stream>>>(w_qkv, WqkvT, D_DIM, 1728);
  transpose_cvt<<<dim3(9, 9), 256, 0, stream>>>(w_out, WoT, D_DIM, D_DIM);
  cvt_kernel<<<288, 256, 0, stream>>>(conv_w, CwB, 128 * D_DIM);

  gemm_mfma<0><<<dim3(32, 27), 256, 0, stream>>>(xb, WqkvT, b_qkv, nullptr, QKb, VbT, nullptr);
  attn_mfma<<<512, 256, 0, stream>>>(QKb, QKb + HSZ, VbT, Opart, Ml);
  attn_merge<<<1152, 256, 0, stream>>>(Opart, Ml, ob);
  gemm_mfma<1><<<dim3(32, 9), 256, 0, stream>>>(ob, WoT, b_out, xb, xr, nullptr, nullptr);
  gemm_mfma<2><<<dim3(32, 2), 256, 0, stream>>>(xr, CwB, nullptr, nullptr, nullptr, nullptr, out);
}

// Round 5
// 287.487 us; speedup vs baseline: 5.4888x; 1.0242x over previous
//
#include <hip/hip_runtime.h>
#include <hip/hip_bf16.h>
#include <math.h>

#define L_TOK 4096
#define D_DIM 576
#define NHEADS 8
#define DHEAD 72
#define DPAD 96
#define HSZ ((size_t)NHEADS * L_TOK * DPAD)   // elems per Q/K/V tensor
#define KSPLIT 3

typedef __attribute__((ext_vector_type(8))) short short8;
typedef __attribute__((ext_vector_type(4))) short short4v;
typedef __attribute__((ext_vector_type(4))) float float4v;

// ---------------------------------------------------------------------------
// K1: unfold 3x3 stride 2 pad 1 -> xb bf16 [4096][576]
// ---------------------------------------------------------------------------
__global__ __launch_bounds__(256) void unfold_kernel(const float* __restrict__ fea,
                                                     __hip_bfloat16* __restrict__ x) {
  int idx = blockIdx.x * 256 + threadIdx.x;   // over 64*4096
  int c = idx >> 12;
  int l = idx & 4095;
  int ho = l >> 6, wo = l & 63;
  const float* f = fea + (size_t)c * (128 * 128);
  __hip_bfloat16* xr = x + (size_t)l * D_DIM + c * 9;
#pragma unroll
  for (int ki = 0; ki < 3; ki++) {
    int h = 2 * ho + ki - 1;
#pragma unroll
    for (int kj = 0; kj < 3; kj++) {
      int w = 2 * wo + kj - 1;
      float v = 0.f;
      if ((unsigned)h < 128u && (unsigned)w < 128u) v = f[h * 128 + w];
      xr[ki * 3 + kj] = __float2bfloat16(v);
    }
  }
}

// ---------------------------------------------------------------------------
// transpose+convert: src fp32 [R][C] -> dst bf16 [C][R]; R,C multiples of 64
// ---------------------------------------------------------------------------
__global__ __launch_bounds__(256) void transpose_cvt(const float* __restrict__ src,
                                                     __hip_bfloat16* __restrict__ dst,
                                                     int R, int C) {
  __shared__ __hip_bfloat16 Ts[64 * 68];
  const int bi = blockIdx.x;  // over C/64
  const int bj = blockIdx.y;  // over R/64
  const int t = threadIdx.x;
  const int col = t & 63, row4 = t >> 6;
#pragma unroll
  for (int u = 0; u < 16; u++) {
    int r = u * 4 + row4;
    Ts[r * 68 + col] = __float2bfloat16(src[(size_t)(bj * 64 + r) * C + bi * 64 + col]);
  }
  __syncthreads();
#pragma unroll
  for (int u = 0; u < 16; u++) {
    int c = u * 4 + row4;
    dst[(size_t)(bi * 64 + c) * R + bj * 64 + col] = Ts[col * 68 + c];
  }
}

// elementwise fp32 -> bf16
__global__ __launch_bounds__(256) void cvt_kernel(const float* __restrict__ src,
                                                  __hip_bfloat16* __restrict__ dst, int n) {
  int i = blockIdx.x * 256 + threadIdx.x;
  if (i < n) dst[i] = __float2bfloat16(src[i]);
}

// ---------------------------------------------------------------------------
// bf16 MFMA GEMM: C[M][N] = A[M][576] @ Bt[N][576]^T (+epilogue)
// BM=128, BN=64, BK=64; 4 waves in 2x2 (wave m-tile 64, n-tile 32).
// EPI: 0 = QKV scatter(+bias): Q,K -> [h][L][96]; V -> VbT [h][96][L]
//      1 = oproj(+bias+residual->bf16), 2 = SiLU+store^T (fp32 out)
// ---------------------------------------------------------------------------
template <int EPI>
__global__ __launch_bounds__(256) void gemm_mfma(const __hip_bfloat16* __restrict__ A,
                                                 const __hip_bfloat16* __restrict__ Bt,
                                                 const float* __restrict__ bias,
                                                 const __hip_bfloat16* __restrict__ resid,
                                                 __hip_bfloat16* __restrict__ outB,
                                                 __hip_bfloat16* __restrict__ outB2,
                                                 float* __restrict__ outF) {
  constexpr int K = D_DIM;
  __shared__ __align__(16) __hip_bfloat16 As[128 * 72];
  __shared__ __align__(16) __hip_bfloat16 Bs[64 * 72];
  const int t = threadIdx.x;
  const int wave = t >> 6, lane = t & 63, quad = lane >> 4, l16 = lane & 15;
  const int wm = (wave & 2) * 32;   // 0 or 64
  const int wn = (wave & 1) * 32;   // 0 or 32
  const int m0 = blockIdx.x * 128, n0 = blockIdx.y * 64;

  float4v acc[4][2];
#pragma unroll
  for (int i = 0; i < 4; i++)
#pragma unroll
    for (int j = 0; j < 2; j++) acc[i][j] = (float4v){0.f, 0.f, 0.f, 0.f};

  const int arow = t >> 3, ach = t & 7;
  for (int k0 = 0; k0 < K; k0 += 64) {
    __syncthreads();
#pragma unroll
    for (int u = 0; u < 4; u++) {
      int row = u * 32 + arow;
      *(float4*)(&As[row * 72 + ach * 8]) =
          *(const float4*)(A + (size_t)(m0 + row) * K + k0 + ach * 8);
    }
#pragma unroll
    for (int u = 0; u < 2; u++) {
      int row = u * 32 + arow;
      *(float4*)(&Bs[row * 72 + ach * 8]) =
          *(const float4*)(Bt + (size_t)(n0 + row) * K + k0 + ach * 8);
    }
    __syncthreads();
    short8 af[4][2], bfr[2][2];
#pragma unroll
    for (int i = 0; i < 4; i++)
#pragma unroll
      for (int s = 0; s < 2; s++)
        af[i][s] = *(const short8*)(&As[(wm + i * 16 + l16) * 72 + s * 32 + quad * 8]);
#pragma unroll
    for (int j = 0; j < 2; j++)
#pragma unroll
      for (int s = 0; s < 2; s++)
        bfr[j][s] = *(const short8*)(&Bs[(wn + j * 16 + l16) * 72 + s * 32 + quad * 8]);
#pragma unroll
    for (int i = 0; i < 4; i++)
#pragma unroll
      for (int j = 0; j < 2; j++) {
        acc[i][j] = __builtin_amdgcn_mfma_f32_16x16x32_bf16(af[i][0], bfr[j][0], acc[i][j], 0, 0, 0);
        acc[i][j] = __builtin_amdgcn_mfma_f32_16x16x32_bf16(af[i][1], bfr[j][1], acc[i][j], 0, 0, 0);
      }
  }

  // epilogue; C/D layout: col = l16 (n), row = quad*4 + r (m)
  if (EPI == 0) {
    const int part = n0 / D_DIM;          // block lies in exactly one of Q/K/V
#pragma unroll
    for (int j = 0; j < 2; j++) {
      int ng = n0 + wn + j * 16 + l16;
      float bv = bias[ng];
      int rem = ng - part * D_DIM;
      int h = rem / DHEAD;
      int d = rem - h * DHEAD;
#pragma unroll
      for (int i = 0; i < 4; i++) {
        int mb = m0 + wm + i * 16 + quad * 4;
#pragma unroll
        for (int r = 0; r < 4; r++) {
          float v = acc[i][j][r] + bv;
          if (part < 2) {
            __hip_bfloat16* dst = outB + (size_t)part * HSZ;
            dst[((size_t)h * L_TOK + mb + r) * DPAD + d] = __float2bfloat16(v);
          } else {
            outB2[((size_t)h * DPAD + d) * L_TOK + mb + r] = __float2bfloat16(v);
          }
        }
      }
    }
  } else if (EPI == 1) {
#pragma unroll
    for (int j = 0; j < 2; j++) {
      int ng = n0 + wn + j * 16 + l16;
      float bv = bias[ng];
#pragma unroll
      for (int i = 0; i < 4; i++) {
        int mb = m0 + wm + i * 16 + quad * 4;
#pragma unroll
        for (int r = 0; r < 4; r++) {
          size_t idx = (size_t)(mb + r) * D_DIM + ng;
          float v = acc[i][j][r] + bv + __bfloat162float(resid[idx]);
          outB[idx] = __float2bfloat16(v);
        }
      }
    }
  } else {
#pragma unroll
    for (int j = 0; j < 2; j++) {
      int ng = n0 + wn + j * 16 + l16;   // output channel, <128
#pragma unroll
      for (int i = 0; i < 4; i++) {
        int mb = m0 + wm + i * 16 + quad * 4;
#pragma unroll
        for (int r = 0; r < 4; r++) {
          float v = acc[i][j][r];
          float sg = 1.f / (1.f + __expf(-v));
          outF[(size_t)ng * L_TOK + mb + r] = v * sg;
        }
      }
    }
  }
}

// ---------------------------------------------------------------------------
// bf16 MFMA flash attention, S^T formulation, K-split by 3 (tiles 22/22/20).
// WG = 4 waves x 32 queries = 128 q; grid 768 = 32 qblk x 3 ksplit x 8 heads.
// S^T = K·Q^T: C-layout col=query(l16), row=key(quad*4+r) -> softmax is
// in-register + 2 cross-quad shuffles. P stored [query][key] (b64-packed),
// PV uses A=P, B=V (from Vt [d][key]) -> O in standard C layout.
// ---------------------------------------------------------------------------
#define KS_STRIDE 104
#define VT_STRIDE 72
#define PS_STRIDE 72

__global__ __launch_bounds__(256) void attn_mfma(const __hip_bfloat16* __restrict__ Qb,
                                                 const __hip_bfloat16* __restrict__ Kb,
                                                 const __hip_bfloat16* __restrict__ VbT,
                                                 __hip_bfloat16* __restrict__ Opart,
                                                 float* __restrict__ Ml) {
  __shared__ __align__(16) __hip_bfloat16 Ks[64 * KS_STRIDE];      // 13312 B
  __shared__ __align__(16) __hip_bfloat16 Vt[80 * VT_STRIDE];      // 11520 B
  __shared__ __align__(16) __hip_bfloat16 Ps[4 * 32 * PS_STRIDE];  // 18432 B

  const int bid = blockIdx.x;
  const int h = bid & 7;                  // head -> XCD affinity
  const int rest = bid >> 3;
  const int ksp = rest % KSPLIT;
  const int qblk = rest / KSPLIT;         // 0..31
  const int t = threadIdx.x;
  const int wave = t >> 6;
  const int lane = t & 63;
  const int quad = lane >> 4;
  const int l16 = lane & 15;

  const __hip_bfloat16* Qh = Qb + (size_t)h * L_TOK * DPAD;
  const __hip_bfloat16* Kh = Kb + (size_t)h * L_TOK * DPAD;
  const __hip_bfloat16* VhT = VbT + (size_t)h * DPAD * L_TOK;

  // Q as MFMA B operand: lane holds Q[q=l16][d=s*32+quad*8+j]; d>=72 pad -> 0
  const int qbase = qblk * 128 + wave * 32;
  short8 qf[2][3];
#pragma unroll
  for (int mi = 0; mi < 2; mi++) {
#pragma unroll
    for (int s = 0; s < 3; s++) {
      if (s == 2 && quad >= 1) {
        qf[mi][s] = (short8){0, 0, 0, 0, 0, 0, 0, 0};
      } else {
        qf[mi][s] = *(const short8*)(Qh + (size_t)(qbase + mi * 16 + l16) * DPAD + s * 32 + quad * 8);
      }
    }
  }

  float4v Of[2][5];
#pragma unroll
  for (int mi = 0; mi < 2; mi++)
#pragma unroll
    for (int nt = 0; nt < 5; nt++) Of[mi][nt] = (float4v){0.f, 0.f, 0.f, 0.f};
  float mrow[2] = {-INFINITY, -INFINITY};   // per-lane stats for query q=l16 (+16*mi)
  float lrow[2] = {0.f, 0.f};
  const float scale = 0.11785113019775792f;  // 72^-0.5

  __hip_bfloat16* myPs = Ps + wave * 32 * PS_STRIDE;
  const int kstart = ksp * 1408;                 // 22 tiles * 64 keys
  const int ntiles = (ksp == 2) ? 20 : 22;
  const float4 zero4 = {0.f, 0.f, 0.f, 0.f};

  for (int kt = 0; kt < ntiles; kt++) {
    const int kbase = kstart + kt * 64;
    __syncthreads();  // prior tile's K/V reads complete

    // stage K tile [64 keys][96 d]; d>=72 forced to zero
#pragma unroll
    for (int u = 0; u < 3; u++) {
      int e = t + u * 256;
      int row = e / 12, ch = e - row * 12;
      if (ch >= 9) {
        *(float4*)(&Ks[row * KS_STRIDE + ch * 8]) = zero4;
      } else {
        *(float4*)(&Ks[row * KS_STRIDE + ch * 8]) =
            *(const float4*)(Kh + (size_t)(kbase + row) * DPAD + ch * 8);
      }
    }
    // stage V^T tile [80 d][64 keys]; rows d>=72 zero
    for (int e = t; e < 640; e += 256) {
      int d = e >> 3, ch = e & 7;
      if (d >= 72) {
        *(float4*)(&Vt[d * VT_STRIDE + ch * 8]) = zero4;
      } else {
        *(float4*)(&Vt[d * VT_STRIDE + ch * 8]) =
            *(const float4*)(VhT + (size_t)d * L_TOK + kbase + ch * 8);
      }
    }
    __syncthreads();

    // S^T = K Q^T: A = K-frag (shared across both query frags), B = Q-frag
    float4v S[2][4];
#pragma unroll
    for (int ks = 0; ks < 4; ks++) {
      float4v a0 = (float4v){0.f, 0.f, 0.f, 0.f};
      float4v a1 = (float4v){0.f, 0.f, 0.f, 0.f};
#pragma unroll
      for (int s = 0; s < 3; s++) {
        short8 kf = *(const short8*)(&Ks[(ks * 16 + l16) * KS_STRIDE + s * 32 + quad * 8]);
        a0 = __builtin_amdgcn_mfma_f32_16x16x32_bf16(kf, qf[0][s], a0, 0, 0, 0);
        a1 = __builtin_amdgcn_mfma_f32_16x16x32_bf16(kf, qf[1][s], a1, 0, 0, 0);
      }
#pragma unroll
      for (int r = 0; r < 4; r++) { S[0][ks][r] = a0[r] * scale; S[1][ks][r] = a1[r] * scale; }
    }

    // softmax: each lane holds 16 scores (keys ks*16+quad*4+r) for query l16
    float alpha[2];
#pragma unroll
    for (int mi = 0; mi < 2; mi++) {
      float tm = -INFINITY;
#pragma unroll
      for (int ks = 0; ks < 4; ks++)
#pragma unroll
        for (int r = 0; r < 4; r++) tm = fmaxf(tm, S[mi][ks][r]);
      tm = fmaxf(tm, __shfl_xor(tm, 16));
      tm = fmaxf(tm, __shfl_xor(tm, 32));
      float mnew = fmaxf(mrow[mi], tm);
      alpha[mi] = __expf(mrow[mi] - mnew);
      mrow[mi] = mnew;
      float ps = 0.f;
#pragma unroll
      for (int ks = 0; ks < 4; ks++)
#pragma unroll
        for (int r = 0; r < 4; r++) {
          float p = __expf(S[mi][ks][r] - mnew);
          ps += p;
          S[mi][ks][r] = p;
        }
      ps += __shfl_xor(ps, 16);
      ps += __shfl_xor(ps, 32);
      lrow[mi] = lrow[mi] * alpha[mi] + ps;
    }

    // P writes: Ps[q][key], 4 consecutive keys packed per ds_write_b64
#pragma unroll
    for (int mi = 0; mi < 2; mi++) {
#pragma unroll
      for (int ks = 0; ks < 4; ks++) {
        union { short4v v; __hip_bfloat16 hh[4]; } pk;
#pragma unroll
        for (int r = 0; r < 4; r++) pk.hh[r] = __float2bfloat16(S[mi][ks][r]);
        *(short4v*)(&myPs[(mi * 16 + l16) * PS_STRIDE + ks * 16 + quad * 4]) = pk.v;
      }
    }

    // redistribute alpha from query=l16 lanes to O-row lanes (row = quad*4+r)
    float aq[2][4];
#pragma unroll
    for (int mi = 0; mi < 2; mi++)
#pragma unroll
      for (int r = 0; r < 4; r++) aq[mi][r] = __shfl(alpha[mi], quad * 4 + r);
#pragma unroll
    for (int mi = 0; mi < 2; mi++)
#pragma unroll
      for (int nt = 0; nt < 5; nt++)
#pragma unroll
        for (int r = 0; r < 4; r++) Of[mi][nt][r] *= aq[mi][r];

    // O += P V : A = P (from myPs, same-wave in-order), B = V (from Vt)
#pragma unroll
    for (int kstep = 0; kstep < 2; kstep++) {
      short8 pa0 = *(const short8*)(&myPs[(0 + l16) * PS_STRIDE + kstep * 32 + quad * 8]);
      short8 pa1 = *(const short8*)(&myPs[(16 + l16) * PS_STRIDE + kstep * 32 + quad * 8]);
#pragma unroll
      for (int nt = 0; nt < 5; nt++) {
        short8 vb = *(const short8*)(&Vt[(nt * 16 + l16) * VT_STRIDE + kstep * 32 + quad * 8]);
        Of[0][nt] = __builtin_amdgcn_mfma_f32_16x16x32_bf16(pa0, vb, Of[0][nt], 0, 0, 0);
        Of[1][nt] = __builtin_amdgcn_mfma_f32_16x16x32_bf16(pa1, vb, Of[1][nt], 0, 0, 0);
      }
    }
  }

  // store unnormalized partials + m,l
  const size_t pb = ((size_t)ksp * NHEADS + h) * L_TOK;
#pragma unroll
  for (int mi = 0; mi < 2; mi++) {
#pragma unroll
    for (int nt = 0; nt < 5; nt++) {
      int d = nt * 16 + l16;
#pragma unroll
      for (int r = 0; r < 4; r++) {
        int q = qbase + mi * 16 + quad * 4 + r;
        Opart[(pb + q) * 80 + d] = __float2bfloat16(Of[mi][nt][r]);
      }
    }
  }
  if (quad == 0) {   // lanes 0..15 hold stats for q = qbase + mi*16 + l16
#pragma unroll
    for (int mi = 0; mi < 2; mi++) {
      int q = qbase + mi * 16 + l16;
      Ml[(pb + q) * 2] = mrow[mi];
      Ml[(pb + q) * 2 + 1] = lrow[mi];
    }
  }
}

// ---------------------------------------------------------------------------
// flash-merge of the KSPLIT partials -> ob[q][h*72+d] bf16
// ---------------------------------------------------------------------------
__global__ __launch_bounds__(256) void attn_merge(const __hip_bfloat16* __restrict__ Opart,
                                                  const float* __restrict__ Ml,
                                                  __hip_bfloat16* __restrict__ ob) {
  int idx = blockIdx.x * 256 + threadIdx.x;     // 8h * 4096q * 9ch
  int h = idx / (L_TOK * 9);
  int rem = idx - h * (L_TOK * 9);
  int q = rem / 9;
  int ch = rem - q * 9;
  size_t b[KSPLIT];
  float m[KSPLIT], l[KSPLIT];
  float mx = -INFINITY;
#pragma unroll
  for (int s = 0; s < KSPLIT; s++) {
    b[s] = ((size_t)s * NHEADS + h) * L_TOK + q;
    m[s] = Ml[b[s] * 2];
    l[s] = Ml[b[s] * 2 + 1];
    mx = fmaxf(mx, m[s]);
  }
  float w[KSPLIT], denom = 0.f;
#pragma unroll
  for (int s = 0; s < KSPLIT; s++) {
    w[s] = __expf(m[s] - mx);
    denom += w[s] * l[s];
  }
  float inv = 1.f / denom;
  float acc[8] = {0, 0, 0, 0, 0, 0, 0, 0};
#pragma unroll
  for (int s = 0; s < KSPLIT; s++) {
    short8 o = *(const short8*)(Opart + b[s] * 80 + ch * 8);
#pragma unroll
    for (int j = 0; j < 8; j++) {
      union { short ss; __hip_bfloat16 bb; } u;
      u.ss = o[j];
      acc[j] += w[s] * __bfloat162float(u.bb);
    }
  }
  __hip_bfloat16* dst = ob + (size_t)q * D_DIM + h * DHEAD + ch * 8;
#pragma unroll
  for (int j = 0; j < 8; j++) dst[j] = __float2bfloat16(acc[j] * inv);
}

// ---------------------------------------------------------------------------
extern "C" void kernel_launch(void* const* d_in, const int* in_sizes, int n_in,
                              void* d_out, int out_size, void* d_ws, size_t ws_size,
                              hipStream_t stream) {
  const float* fea    = (const float*)d_in[0];
  const float* w_qkv  = (const float*)d_in[1];
  const float* b_qkv  = (const float*)d_in[2];
  const float* w_out  = (const float*)d_in[3];
  const float* b_out  = (const float*)d_in[4];
  const float* conv_w = (const float*)d_in[5];
  float* out = (float*)d_out;

  __hip_bfloat16* xb    = (__hip_bfloat16*)d_ws;             // 4096*576
  __hip_bfloat16* WqkvT = xb + (size_t)L_TOK * D_DIM;        // 1728*576
  __hip_bfloat16* WoT   = WqkvT + (size_t)1728 * D_DIM;      // 576*576
  __hip_bfloat16* CwB   = WoT + (size_t)D_DIM * D_DIM;       // 128*576
  __hip_bfloat16* QKb   = CwB + (size_t)128 * D_DIM;         // 2 * HSZ (Q,K)
  __hip_bfloat16* VbT   = QKb + 2 * HSZ;                     // HSZ
  __hip_bfloat16* ob    = VbT + HSZ;                         // 4096*576
  __hip_bfloat16* xr    = ob + (size_t)L_TOK * D_DIM;        // 4096*576
  __hip_bfloat16* Opart = xr + (size_t)L_TOK * D_DIM;        // KSPLIT*8*4096*80
  float* Ml = (float*)(Opart + (size_t)KSPLIT * NHEADS * L_TOK * 80);  // KSPLIT*8*4096*2

  unfold_kernel<<<1024, 256, 0, stream>>>(fea, xb);
  transpose_cvt<<<dim3(27, 9), 256, 0, stream>>>(w_qkv, WqkvT, D_DIM, 1728);
  transpose_cvt<<<dim3(9, 9), 256, 0, stream>>>(w_out, WoT, D_DIM, D_DIM);
  cvt_kernel<<<288, 256, 0, stream>>>(conv_w, CwB, 128 * D_DIM);

  gemm_mfma<0><<<dim3(32, 27), 256, 0, stream>>>(xb, WqkvT, b_qkv, nullptr, QKb, VbT, nullptr);
  attn_mfma<<<768, 256, 0, stream>>>(QKb, QKb + HSZ, VbT, Opart, Ml);
  attn_merge<<<1152, 256, 0, stream>>>(Opart, Ml, ob);
  gemm_mfma<1><<<dim3(32, 9), 256, 0, stream>>>(ob, WoT, b_out, xb, xr, nullptr, nullptr);
  gemm_mfma<2><<<dim3(32, 2), 256, 0, stream>>>(xr, CwB, nullptr, nullptr, nullptr, nullptr, out);
}